// Round 2
// baseline (508.157 us; speedup 1.0000x reference)
//
#include <hip/hip_runtime.h>
#include <hip/hip_fp16.h>

// ScaledDotProductAttention: context = softmax(QK^T/sqrt(d) - 100*mask) @ V
// B=32 Tq=2048 Tk=1024 d=128 dv=256, fp32 in/out.
// R2: fused TWO-PASS kernel (pass A: rowsums; pass B: recompute S -> write
// normalized score + PV). Removes the 128KB P LDS buffer -> 56.5 KB LDS ->
// 2 wgs/CU, launch_bounds(512,4) caps VGPR<=128 -> 16 waves/CU.

namespace {

constexpr int kB = 32, kTq = 2048, kTk = 1024, kD = 128, kDv = 256;
constexpr int kBQ = 64;       // q rows per workgroup
constexpr int kBK = 64;       // key tile
constexpr float kScale = 0.08838834764831845f;  // 1/sqrt(128)

typedef _Float16 half8 __attribute__((ext_vector_type(8)));
typedef _Float16 half4 __attribute__((ext_vector_type(4)));
typedef float    f32x4 __attribute__((ext_vector_type(4)));
typedef float    f32x2 __attribute__((ext_vector_type(2)));

// LDS map (bytes)
constexpr int kOffK   = 0;      // K tile  [64 keys][128 d] f16, swizzled (16384)
constexpr int kOffV   = 16384;  // V^T     [256 dv][64 keys] f16, swizzled (32768)
constexpr int kOffP   = 49152;  // P tile  [64 q][64 keys]  f16, swizzled (8192)
constexpr int kOffSum = 57344;  // rowsum[64] f32 (256)
constexpr int kLds    = 57600;

__device__ __forceinline__ int kswz(int row, int cb) {  // row<64, cb<256
  return kOffK + row * 256 + (cb ^ ((row & 7) << 4));
}
__device__ __forceinline__ int vswz(int dv, int kb) {   // dv<256, kb<128
  return kOffV + dv * 128 + (kb ^ ((dv & 7) << 4));
}
__device__ __forceinline__ int pswz(int row, int kb) {  // row<64, kb<128
  return kOffP + row * 128 + (kb ^ ((row & 7) << 4));
}

__global__ __launch_bounds__(512, 4)
void attn_fused(const float* __restrict__ qg, const float* __restrict__ kg,
                const float* __restrict__ vg, const float* __restrict__ mg,
                float* __restrict__ out) {
  __shared__ __align__(16) unsigned char s_[kLds];
  float* rowsum = (float*)(s_ + kOffSum);

  const int tid  = threadIdx.x;
  const int lane = tid & 63;
  const int wid  = tid >> 6;     // 0..7
  const int l15  = lane & 15;
  const int lg   = lane >> 4;    // 0..3

  // XCD-friendly mapping: all 32 q-blocks of a batch on one XCD
  const int bi    = blockIdx.x;
  const int batch = (bi & 7) * 4 + (bi >> 8);
  const int q0    = ((bi >> 3) & 31) * kBQ;

  const float* Q = qg + ((size_t)batch * kTq + q0) * kD;
  const float* K = kg + (size_t)batch * kTk * kD;
  const float* V = vg + (size_t)batch * kTk * kDv;
  const float* M = mg + ((size_t)batch * kTq + q0) * kTk;
  float* CTX = out + ((size_t)batch * kTq + q0) * kDv;
  float* SCR = out + (size_t)kB * kTq * kDv + ((size_t)batch * kTq + q0) * kTk;

  if (tid < kBQ) rowsum[tid] = 0.f;

  // wave tiling: QK^T -> wave owns 16 q rows x 32 keys; PV -> 16 q x 128 dv
  const int wr = wid >> 1;   // 0..3
  const int wc = wid & 1;    // 0..1

  // ---- Q fragments (16 rows x 128 d per wave) ----
  half8 qf[4];
  {
    const float* qrow = Q + (size_t)(wr * 16 + l15) * kD + lg * 8;
#pragma unroll
    for (int c = 0; c < 4; ++c) {
      f32x4 a = *(const f32x4*)(qrow + c * 32);
      f32x4 b = *(const f32x4*)(qrow + c * 32 + 4);
      half8 h;
      h[0] = a[0]; h[1] = a[1]; h[2] = a[2]; h[3] = a[3];
      h[4] = b[0]; h[5] = b[1]; h[6] = b[2]; h[7] = b[3];
      qf[c] = h;
    }
  }

  // K staging thread roles
  const int srow = tid >> 5;          // 0..15
  const int scol = (tid & 31) * 4;    // float col
  // V staging thread roles: thread -> (dv pair vc2, key octet vh)
  const int vh  = tid >> 7;           // 0..3
  const int vc2 = (tid & 127) * 2;    // 0..254

  // ================= PASS A: rowsums =================
  f32x4 st[4];
#pragma unroll
  for (int s = 0; s < 4; ++s)
    st[s] = *(const f32x4*)(K + (size_t)(s * 16 + srow) * kD + scol);

  float rsum[4] = {0.f, 0.f, 0.f, 0.f};
  constexpr int kSteps = kTk / kBK;   // 16
  for (int step = 0; step < kSteps; ++step) {
    __syncthreads();
#pragma unroll
    for (int s = 0; s < 4; ++s) {
      half4 h; h[0] = st[s][0]; h[1] = st[s][1]; h[2] = st[s][2]; h[3] = st[s][3];
      *(half4*)(s_ + kswz(s * 16 + srow, scol * 2)) = h;
    }
    __syncthreads();
    if (step + 1 < kSteps) {
      const float* Kn = K + (size_t)(step + 1) * kBK * kD;
#pragma unroll
      for (int s = 0; s < 4; ++s)
        st[s] = *(const f32x4*)(Kn + (size_t)(s * 16 + srow) * kD + scol);
    }
    float mv[2][4];
#pragma unroll
    for (int t = 0; t < 2; ++t)
#pragma unroll
      for (int j = 0; j < 4; ++j)
        mv[t][j] = M[(size_t)(wr * 16 + lg * 4 + j) * kTk +
                     step * kBK + wc * 32 + t * 16 + l15];
    f32x4 acc[2] = {{0, 0, 0, 0}, {0, 0, 0, 0}};
    __builtin_amdgcn_s_setprio(1);
#pragma unroll
    for (int c = 0; c < 4; ++c) {
#pragma unroll
      for (int t = 0; t < 2; ++t) {
        half8 bf = *(const half8*)(s_ + kswz(wc * 32 + t * 16 + l15, c * 64 + lg * 16));
        acc[t] = __builtin_amdgcn_mfma_f32_16x16x32_f16(qf[c], bf, acc[t], 0, 0, 0);
      }
    }
    __builtin_amdgcn_s_setprio(0);
#pragma unroll
    for (int t = 0; t < 2; ++t)
#pragma unroll
      for (int j = 0; j < 4; ++j)
        rsum[j] += __expf(acc[t][j] * kScale - 100.f * mv[t][j]);
  }

  // ---- V sub-tile 0 loads issued early (hide under the reduce) ----
  f32x2 vv[8];
#pragma unroll
  for (int j = 0; j < 8; ++j)
    vv[j] = *(const f32x2*)(V + (size_t)(vh * 8 + j) * kDv + vc2);

  // ---- finalize rowsums -> reciprocals ----
#pragma unroll
  for (int m = 1; m <= 8; m <<= 1)
#pragma unroll
    for (int j = 0; j < 4; ++j) rsum[j] += __shfl_xor(rsum[j], m);
  if (l15 == 0) {
#pragma unroll
    for (int j = 0; j < 4; ++j)
      atomicAdd(&rowsum[wr * 16 + lg * 4 + j], rsum[j]);
  }
  __syncthreads();
  if (tid < kBQ) rowsum[tid] = 1.0f / rowsum[tid];
  __syncthreads();
  float invj[4];
#pragma unroll
  for (int j = 0; j < 4; ++j) invj[j] = rowsum[wr * 16 + lg * 4 + j];

  // ================= PASS B: score + PV =================
  // prologue: write V sub0 -> half0; prefetch V sub1; prefetch K tile0
  {
    half8 h0, h1;
#pragma unroll
    for (int j = 0; j < 8; ++j) { h0[j] = vv[j][0]; h1[j] = vv[j][1]; }
    *(half8*)(s_ + vswz(vc2,     vh * 16)) = h0;
    *(half8*)(s_ + vswz(vc2 + 1, vh * 16)) = h1;
  }
#pragma unroll
  for (int j = 0; j < 8; ++j)
    vv[j] = *(const f32x2*)(V + (size_t)(32 + vh * 8 + j) * kDv + vc2);
#pragma unroll
  for (int s = 0; s < 4; ++s)
    st[s] = *(const f32x4*)(K + (size_t)(s * 16 + srow) * kD + scol);

  f32x4 acc4[8];
#pragma unroll
  for (int t = 0; t < 8; ++t) acc4[t] = (f32x4){0, 0, 0, 0};

  for (int step = 0; step < kSteps; ++step) {
    __syncthreads();  // (a) prior reads of s_k/s_p/s_v-half1 complete
    // stage K tile + V odd sub-tile (2*step+1) -> half1
#pragma unroll
    for (int s = 0; s < 4; ++s) {
      half4 h; h[0] = st[s][0]; h[1] = st[s][1]; h[2] = st[s][2]; h[3] = st[s][3];
      *(half4*)(s_ + kswz(s * 16 + srow, scol * 2)) = h;
    }
    {
      half8 h0, h1;
#pragma unroll
      for (int j = 0; j < 8; ++j) { h0[j] = vv[j][0]; h1[j] = vv[j][1]; }
      *(half8*)(s_ + vswz(vc2,     64 + vh * 16)) = h0;
      *(half8*)(s_ + vswz(vc2 + 1, 64 + vh * 16)) = h1;
    }
    __syncthreads();  // (b)
    // prefetches (hide under QK^T phase)
    if (step + 1 < kSteps) {
      const float* Kn = K + (size_t)(step + 1) * kBK * kD;
#pragma unroll
      for (int s = 0; s < 4; ++s)
        st[s] = *(const f32x4*)(Kn + (size_t)(s * 16 + srow) * kD + scol);
#pragma unroll
      for (int j = 0; j < 8; ++j)   // V sub 2*step+2 (next tile half0)
        vv[j] = *(const f32x2*)(V + (size_t)((step + 1) * 64 + vh * 8 + j) * kDv + vc2);
    }
    float mv[2][4];
#pragma unroll
    for (int t = 0; t < 2; ++t)
#pragma unroll
      for (int j = 0; j < 4; ++j)
        mv[t][j] = M[(size_t)(wr * 16 + lg * 4 + j) * kTk +
                     step * kBK + wc * 32 + t * 16 + l15];
    f32x4 acc[2] = {{0, 0, 0, 0}, {0, 0, 0, 0}};
    __builtin_amdgcn_s_setprio(1);
#pragma unroll
    for (int c = 0; c < 4; ++c) {
#pragma unroll
      for (int t = 0; t < 2; ++t) {
        half8 bf = *(const half8*)(s_ + kswz(wc * 32 + t * 16 + l15, c * 64 + lg * 16));
        acc[t] = __builtin_amdgcn_mfma_f32_16x16x32_f16(qf[c], bf, acc[t], 0, 0, 0);
      }
    }
    __builtin_amdgcn_s_setprio(0);
    // normalized score -> global + P tile (fp16) -> LDS
#pragma unroll
    for (int t = 0; t < 2; ++t)
#pragma unroll
      for (int j = 0; j < 4; ++j) {
        float e = __expf(acc[t][j] * kScale - 100.f * mv[t][j]);
        float p = e * invj[j];
        int row = wr * 16 + lg * 4 + j;
        int col = wc * 32 + t * 16 + l15;
        SCR[(size_t)row * kTk + step * kBK + col] = p;
        *(_Float16*)(s_ + pswz(row, col * 2)) = (_Float16)p;
      }
    __syncthreads();  // (c) s_p ready; V half0/half1 ready
    // PV: 16 q x 128 dv per wave, K=64
    {
      int arow = wr * 16 + l15;
      half8 af0 = *(const half8*)(s_ + pswz(arow, lg * 16));
      half8 af1 = *(const half8*)(s_ + pswz(arow, 64 + lg * 16));
      __builtin_amdgcn_s_setprio(1);
#pragma unroll
      for (int t = 0; t < 8; ++t) {
        int vc = wc * 128 + t * 16 + l15;
        half8 b0 = *(const half8*)(s_ + vswz(vc, lg * 16));
        acc4[t] = __builtin_amdgcn_mfma_f32_16x16x32_f16(af0, b0, acc4[t], 0, 0, 0);
        half8 b1 = *(const half8*)(s_ + vswz(vc, 64 + lg * 16));
        acc4[t] = __builtin_amdgcn_mfma_f32_16x16x32_f16(af1, b1, acc4[t], 0, 0, 0);
      }
      __builtin_amdgcn_s_setprio(0);
    }
    __syncthreads();  // (d) PV reads of half0 done
    if (step + 1 < kSteps) {
      // write V sub 2*step+2 -> half0; prefetch V sub 2*step+3
      half8 h0, h1;
#pragma unroll
      for (int j = 0; j < 8; ++j) { h0[j] = vv[j][0]; h1[j] = vv[j][1]; }
      *(half8*)(s_ + vswz(vc2,     vh * 16)) = h0;
      *(half8*)(s_ + vswz(vc2 + 1, vh * 16)) = h1;
#pragma unroll
      for (int j = 0; j < 8; ++j)
        vv[j] = *(const f32x2*)(V + (size_t)((step + 1) * 64 + 32 + vh * 8 + j) * kDv + vc2);
    }
  }

  // epilogue: context store (already normalized)
#pragma unroll
  for (int t = 0; t < 8; ++t)
#pragma unroll
    for (int j = 0; j < 4; ++j)
      CTX[(size_t)(wr * 16 + lg * 4 + j) * kDv + wc * 128 + t * 16 + l15] = acc4[t][j];
}

}  // namespace

extern "C" void kernel_launch(void* const* d_in, const int* in_sizes, int n_in,
                              void* d_out, int out_size, void* d_ws, size_t ws_size,
                              hipStream_t stream) {
  const float* q = (const float*)d_in[0];
  const float* k = (const float*)d_in[1];
  const float* v = (const float*)d_in[2];
  const float* m = (const float*)d_in[3];
  float* out = (float*)d_out;
  (void)in_sizes; (void)n_in; (void)out_size; (void)d_ws; (void)ws_size;

  dim3 grid(kB * (kTq / kBQ));   // 1024 workgroups
  dim3 block(512);
  hipLaunchKernelGGL(attn_fused, grid, block, 0, stream, q, k, v, m, out);
}

// Round 3
// 307.237 us; speedup vs baseline: 1.6540x; 1.6540x over previous
//
#include <hip/hip_runtime.h>
#include <hip/hip_fp16.h>

// ScaledDotProductAttention: context = softmax(QK^T/sqrt(d) - 100*mask) @ V
// B=32 Tq=2048 Tk=1024 d=128 dv=256, fp32 in/out.
// R3: back to R1's traffic-optimal single-pass (P fp16 in LDS, score written
// once, normalized, fully coalesced) but with 1024 threads (16 waves = 4/SIMD,
// 2x R1 occupancy), mask prefetch, swizzled V^T staging, setprio on MFMA.

namespace {

constexpr int kB = 32, kTq = 2048, kTk = 1024, kD = 128, kDv = 256;
constexpr int kBQ  = 64;   // q rows per workgroup
constexpr int kBK  = 64;   // key tile (QK^T)
constexpr int kBK2 = 32;   // key tile (PV)
constexpr float kScale = 0.08838834764831845f;  // 1/sqrt(128)

typedef _Float16 half8 __attribute__((ext_vector_type(8)));
typedef _Float16 half4 __attribute__((ext_vector_type(4)));
typedef float    f32x4 __attribute__((ext_vector_type(4)));

// LDS map (bytes)
constexpr int kOffP   = 0;        // P [64 q][1024 k] fp16 swizzled   (131072)
constexpr int kOffK   = 131072;   // K tile [64 k][128 d] f16 swz / V^T [256 dv][32 k] f16 swz (16384)
constexpr int kOffSum = 147456;   // rowsum[64] f32
constexpr int kLds    = 147712;

__device__ __forceinline__ int pswz(int row, int cb) {  // row<64, cb<2048
  return kOffP + row * 2048 + (cb ^ ((row & 7) << 4));
}
__device__ __forceinline__ int kswz(int row, int cb) {  // row<64, cb<256
  return kOffK + row * 256 + (cb ^ ((row & 7) << 4));
}
__device__ __forceinline__ int vswz(int dv, int kb) {   // dv<256, kb<64
  return kOffK + dv * 64 + (kb ^ ((dv & 3) << 4));
}

__global__ __launch_bounds__(1024, 4)
void attn_fused(const float* __restrict__ qg, const float* __restrict__ kg,
                const float* __restrict__ vg, const float* __restrict__ mg,
                float* __restrict__ out) {
  __shared__ __align__(16) unsigned char s_[kLds];
  float* rowsum = (float*)(s_ + kOffSum);

  const int tid  = threadIdx.x;
  const int lane = tid & 63;
  const int wid  = tid >> 6;     // 0..15
  const int l15  = lane & 15;
  const int lg   = lane >> 4;    // 0..3

  // XCD-friendly mapping: all 32 q-blocks of a batch land on one XCD
  const int bi    = blockIdx.x;
  const int batch = (bi & 7) * 4 + (bi >> 8);
  const int q0    = ((bi >> 3) & 31) * kBQ;

  const float* Q = qg + ((size_t)batch * kTq + q0) * kD;
  const float* K = kg + (size_t)batch * kTk * kD;
  const float* V = vg + (size_t)batch * kTk * kDv;
  const float* M = mg + ((size_t)batch * kTq + q0) * kTk;
  float* CTX = out + ((size_t)batch * kTq + q0) * kDv;
  float* SCR = out + (size_t)kB * kTq * kDv + ((size_t)batch * kTq + q0) * kTk;

  if (tid < kBQ) rowsum[tid] = 0.f;   // ordered by first loop barrier

  // wave tiling (phase 1): wave owns 16 q rows x 16 keys of each 64-key tile
  const int wr = wid >> 2;   // 0..3 : q row group
  const int wc = wid & 3;    // 0..3 : key col group

  // ---- Q fragments (16 rows x 128 d per wave) ----
  half8 qf[4];
  {
    const float* qrow = Q + (size_t)(wr * 16 + l15) * kD + lg * 8;
#pragma unroll
    for (int c = 0; c < 4; ++c) {
      f32x4 a = *(const f32x4*)(qrow + c * 32);
      f32x4 b = *(const f32x4*)(qrow + c * 32 + 4);
      half8 h;
      h[0] = a[0]; h[1] = a[1]; h[2] = a[2]; h[3] = a[3];
      h[4] = b[0]; h[5] = b[1]; h[6] = b[2]; h[7] = b[3];
      qf[c] = h;
    }
  }

  // ================= Phase 1: S=QK^T, e=exp -> P(LDS), rowsums =================
  const int srow = tid >> 4;          // 0..63 (K staging row)
  const int scol = (tid & 15) * 8;    // float col (8 floats per thread)
  f32x4 st0 = *(const f32x4*)(K + (size_t)srow * kD + scol);
  f32x4 st1 = *(const f32x4*)(K + (size_t)srow * kD + scol + 4);

  float mv[4], mvN[4];
#pragma unroll
  for (int j = 0; j < 4; ++j)
    mv[j] = M[(size_t)(wr * 16 + lg * 4 + j) * kTk + wc * 16 + l15];

  float rsum[4] = {0.f, 0.f, 0.f, 0.f};
  constexpr int kSteps = kTk / kBK;   // 16
  for (int step = 0; step < kSteps; ++step) {
    __syncthreads();                  // prior K-tile reads done
    {
      half8 h;
      h[0] = st0[0]; h[1] = st0[1]; h[2] = st0[2]; h[3] = st0[3];
      h[4] = st1[0]; h[5] = st1[1]; h[6] = st1[2]; h[7] = st1[3];
      *(half8*)(s_ + kswz(srow, scol * 2)) = h;
    }
    __syncthreads();
    if (step + 1 < kSteps) {          // prefetch next K tile + next mask (in
      const float* Kn = K + (size_t)(step + 1) * kBK * kD;  // flight during MFMA)
      st0 = *(const f32x4*)(Kn + (size_t)srow * kD + scol);
      st1 = *(const f32x4*)(Kn + (size_t)srow * kD + scol + 4);
#pragma unroll
      for (int j = 0; j < 4; ++j)
        mvN[j] = M[(size_t)(wr * 16 + lg * 4 + j) * kTk +
                   (step + 1) * kBK + wc * 16 + l15];
    }
    f32x4 acc = {0.f, 0.f, 0.f, 0.f};
    __builtin_amdgcn_s_setprio(1);
#pragma unroll
    for (int c = 0; c < 4; ++c) {
      half8 bf = *(const half8*)(s_ + kswz(wc * 16 + l15, c * 64 + lg * 16));
      acc = __builtin_amdgcn_mfma_f32_16x16x32_f16(qf[c], bf, acc, 0, 0, 0);
    }
    __builtin_amdgcn_s_setprio(0);
#pragma unroll
    for (int j = 0; j < 4; ++j) {
      float e = __expf(acc[j] * kScale - 100.f * mv[j]);
      rsum[j] += e;
      *(_Float16*)(s_ + pswz(wr * 16 + lg * 4 + j,
                             (step * kBK + wc * 16 + l15) * 2)) = (_Float16)e;
    }
#pragma unroll
    for (int j = 0; j < 4; ++j) mv[j] = mvN[j];
  }

  // ================= Phase 2: rowsums -> reciprocals =================
  __syncthreads();
#pragma unroll
  for (int m = 1; m <= 8; m <<= 1)
#pragma unroll
    for (int j = 0; j < 4; ++j) rsum[j] += __shfl_xor(rsum[j], m);
  if (l15 == 0) {
#pragma unroll
    for (int j = 0; j < 4; ++j)
      atomicAdd(&rowsum[wr * 16 + lg * 4 + j], rsum[j]);
  }
  __syncthreads();
  if (tid < kBQ) rowsum[tid] = 1.0f / rowsum[tid];
  __syncthreads();

  // ---- V tile-0 loads issued early (hide under score writes) ----
  const int vcol = tid & 255;   // dv column
  const int vkh  = tid >> 8;    // key octet 0..3
  float vst[8];
#pragma unroll
  for (int j = 0; j < 8; ++j)
    vst[j] = V[(size_t)(vkh * 8 + j) * kDv + vcol];

  // ================= Phase 3: normalized score write (coalesced f32x4) ========
#pragma unroll
  for (int rr = 0; rr < 4; ++rr) {
    int row = wid * 4 + rr;
    float inv = rowsum[row];
#pragma unroll
    for (int it = 0; it < 4; ++it) {
      int col = it * 256 + lane * 4;
      half4 hv = *(const half4*)(s_ + pswz(row, col * 2));
      f32x4 o;
      o[0] = (float)hv[0] * inv; o[1] = (float)hv[1] * inv;
      o[2] = (float)hv[2] * inv; o[3] = (float)hv[3] * inv;
      *(f32x4*)(SCR + (size_t)row * kTk + col) = o;
    }
  }

  // ================= Phase 4: context = (P @ V) * inv =================
  const int wr4 = wid >> 2;   // 0..3 : q row group (16 rows)
  const int wc4 = wid & 3;    // 0..3 : dv col group (64 cols)
  f32x4 acc4[4];
#pragma unroll
  for (int t = 0; t < 4; ++t) acc4[t] = (f32x4){0, 0, 0, 0};

  constexpr int kSteps4 = kTk / kBK2;   // 32
  for (int step = 0; step < kSteps4; ++step) {
    __syncthreads();                    // V^T region free
    {
      half8 h;
#pragma unroll
      for (int j = 0; j < 8; ++j) h[j] = vst[j];
      *(half8*)(s_ + vswz(vcol, vkh * 16)) = h;
    }
    __syncthreads();
    if (step + 1 < kSteps4) {           // prefetch next V tile (flies over MFMA)
      const float* Vn = V + (size_t)(step + 1) * kBK2 * kDv;
#pragma unroll
      for (int j = 0; j < 8; ++j)
        vst[j] = Vn[(size_t)(vkh * 8 + j) * kDv + vcol];
    }
    int arow = wr4 * 16 + l15;
    half8 af = *(const half8*)(s_ + pswz(arow, step * 64 + lg * 16));
    __builtin_amdgcn_s_setprio(1);
#pragma unroll
    for (int t = 0; t < 4; ++t) {
      half8 bf = *(const half8*)(s_ + vswz(wc4 * 64 + t * 16 + l15, lg * 16));
      acc4[t] = __builtin_amdgcn_mfma_f32_16x16x32_f16(af, bf, acc4[t], 0, 0, 0);
    }
    __builtin_amdgcn_s_setprio(0);
  }

  // epilogue: scale by 1/rowsum, store context
  float invr[4];
#pragma unroll
  for (int j = 0; j < 4; ++j) invr[j] = rowsum[wr4 * 16 + lg * 4 + j];
#pragma unroll
  for (int t = 0; t < 4; ++t)
#pragma unroll
    for (int j = 0; j < 4; ++j)
      CTX[(size_t)(wr4 * 16 + lg * 4 + j) * kDv + wc4 * 64 + t * 16 + l15] =
          acc4[t][j] * invr[j];
}

}  // namespace

extern "C" void kernel_launch(void* const* d_in, const int* in_sizes, int n_in,
                              void* d_out, int out_size, void* d_ws, size_t ws_size,
                              hipStream_t stream) {
  const float* q = (const float*)d_in[0];
  const float* k = (const float*)d_in[1];
  const float* v = (const float*)d_in[2];
  const float* m = (const float*)d_in[3];
  float* out = (float*)d_out;
  (void)in_sizes; (void)n_in; (void)out_size; (void)d_ws; (void)ws_size;

  dim3 grid(kB * (kTq / kBQ));   // 1024 workgroups
  dim3 block(1024);
  hipLaunchKernelGGL(attn_fused, grid, block, 0, stream, q, k, v, m, out);
}